// Round 1
// baseline (126.987 us; speedup 1.0000x reference)
//
#include <hip/hip_runtime.h>
#include <math.h>

// Problem dims
#define DM 512
#define DD 64
#define KK 64
#define BB 4096

// Workspace layout (float offsets)
#define WS_INV   0
#define WS_CONST 1
#define WS_W     16
#define WS_WV2   (WS_W + 512)     // 528
#define WS_T     (WS_WV2 + 512)   // 1040
#define WS_CVW   (WS_T + 512)     // 1552
#define WS_CK0   (WS_CVW + 64)    // 1616
#define WS_NY2   (WS_CK0 + 64)    // 1680
#define WS_YT    (WS_NY2 + 64)    // 1744
#define WS_GT    (WS_YT + 4096)   // 5840
#define WS_P1    (WS_GT + 4096)   // 9936
// total: 9936 + 32768 = 42704 floats (~171 KB)

__device__ __forceinline__ float wave_sum(float x) {
#pragma unroll
    for (int o = 32; o; o >>= 1) x += __shfl_xor(x, o);
    return x;
}

// 512-thread (8-wave) block sum; every thread gets the full sum.
__device__ __forceinline__ float block_sum512(float v, float* red) {
    float s = wave_sum(v);
    const int wid = threadIdx.x >> 6;
    __syncthreads();                      // protect red reuse across calls
    if ((threadIdx.x & 63) == 0) red[wid] = s;
    __syncthreads();
    float t2 = 0.0f;
#pragma unroll
    for (int i = 0; i < 8; ++i) t2 += red[i];
    return t2;
}

// ---------------------------------------------------------------------------
// K1: single block, 512 threads.
//  - power iteration on zW [512x64]  -> inv_sigma
//  - spectral chain on vW [1x512]    -> w = vW/sigma_v
//  - const_part = bo.w + vb
//  - project chart_centers -> y^T [64x64], ny2[64]
// ---------------------------------------------------------------------------
__global__ __launch_bounds__(512) void k_setup(
    const float* __restrict__ zW, const float* __restrict__ vW,
    const float* __restrict__ bo, const float* __restrict__ vb,
    const float* __restrict__ cc, float* __restrict__ ws)
{
    __shared__ float ush[512];
    __shared__ float vsh[64];
    __shared__ float part[8][64];
    __shared__ float red[8];
    const int t = threadIdx.x;
    const int d = t & 63, ch = t >> 6;

    // ---- zW power iteration (u in R^512, v in R^64) ----
    ush[t] = 1.0f / (sqrtf(512.0f) + 1e-12f);   // l2n(ones(512))
    __syncthreads();
    float upre = 0.0f;
    for (int it = 0; it < 5; ++it) {
        // v = l2n(zW^T @ u): thread (ch,d) does a 64-chunk partial
        float pv = 0.0f;
#pragma unroll 4
        for (int i = ch * 64; i < ch * 64 + 64; ++i)
            pv = fmaf(zW[i * 64 + d], ush[i], pv);
        part[ch][d] = pv;
        __syncthreads();
        if (t < 64) {
            float vd = 0.0f;
#pragma unroll
            for (int c = 0; c < 8; ++c) vd += part[c][t];
            const float nv = sqrtf(wave_sum(vd * vd));
            vsh[t] = vd / (nv + 1e-12f);
        }
        __syncthreads();
        // u = l2n(zW @ v)
        float ui = 0.0f;
#pragma unroll 4
        for (int dd = 0; dd < 64; ++dd)
            ui = fmaf(zW[t * 64 + dd], vsh[dd], ui);
        upre = ui;
        const float nu = sqrtf(block_sum512(ui * ui, red));
        ush[t] = ui / (nu + 1e-12f);
        __syncthreads();
    }
    {
        const float sig = block_sum512(ush[t] * upre, red);
        if (t == 0) ws[WS_INV] = 1.0f / sig;
    }

    // ---- vW spectral chain (u scalar, v in R^512) ----
    const float vwt = vW[t];
    float uv = 1.0f / (1.0f + 1e-12f);          // l2n(ones(1))
    float s = 0.0f;
    for (int it = 0; it < 5; ++it) {
        const float tv = vwt * uv;              // W^T u
        const float nv = sqrtf(block_sum512(tv * tv, red));
        const float vcur = tv / (nv + 1e-12f);  // v = l2n(.)
        s = block_sum512(vwt * vcur, red);      // W @ v (scalar)
        uv = s / (fabsf(s) + 1e-12f);           // u = l2n(.)
    }
    const float sigv = uv * s;                  // u @ (W @ v)
    const float wv = vwt / sigv;                // scaled weight row
    ws[WS_W + t] = wv;
    {
        const float cp = block_sum512(bo[t] * wv, red);
        if (t == 0) ws[WS_CONST] = cp + vb[0];
    }

    // ---- project chart_centers to ball; store y^T and ||y||^2 ----
    if (t < 64) {
        float n2 = 0.0f;
        for (int dd = 0; dd < 64; ++dd) {
            const float c = cc[t * 64 + dd];
            n2 = fmaf(c, c, n2);
        }
        const float n = sqrtf(n2);
        const float scale = fminf(1.0f, (1.0f - 1e-5f) / fmaxf(n, 1e-12f));
        float s2 = 0.0f;
        for (int dd = 0; dd < 64; ++dd) {
            const float yv = cc[t * 64 + dd] * scale;
            ws[WS_YT + dd * 64 + t] = yv;       // transposed [d][k]
            s2 = fmaf(yv, yv, s2);
        }
        ws[WS_NY2 + t] = s2;
    }
}

// ---------------------------------------------------------------------------
// K2: 80 blocks x 512 threads.
//  blocks 0..63 : P1[f,d] = inv_sigma * sum_e Wq[f,e]*zW[e,d]   (8 f-rows each)
//  blocks 64..71: wo[e] = sum_g Wo[g,e]*w[g] (in LDS), then
//                 wv2 f-tile: wv2[f] = sum_e wo[e]*Wv[e,f]
//                 block 64 also finalizes const += bv.wo
//  blocks 72..79: qzb[f] = sum_e Wq[f,e]*zb[e] + bq[f] (in LDS), then
//                 t c-tile:  t[c] = sum_f qzb[f]*Wk[f,c]
// ---------------------------------------------------------------------------
__global__ __launch_bounds__(512) void k_mats(
    const float* __restrict__ zW, const float* __restrict__ Wq,
    const float* __restrict__ Wo, const float* __restrict__ Wv,
    const float* __restrict__ Wk, const float* __restrict__ zb,
    const float* __restrict__ bq, const float* __restrict__ bv,
    float* __restrict__ ws)
{
    __shared__ float sh[512];
    __shared__ float sh2[512];
    __shared__ float part[8][64];
    __shared__ float red[8];
    const int blk = blockIdx.x, t = threadIdx.x;

    if (blk < 64) {
        const float inv_s = ws[WS_INV];
        const int fi = t >> 6, d = t & 63;
        const int f = blk * 8 + fi;
        float acc = 0.0f;
        for (int e = 0; e < 512; ++e)
            acc = fmaf(Wq[f * 512 + e], zW[e * 64 + d], acc);
        ws[WS_P1 + f * 64 + d] = acc * inv_s;
    } else if (blk < 72) {
        sh[t] = ws[WS_W + t];
        __syncthreads();
        float wo = 0.0f;
        for (int g = 0; g < 512; ++g)
            wo = fmaf(Wo[g * 512 + t], sh[g], wo);   // coalesced in t
        sh2[t] = wo;
        if (blk == 64) {
            const float c2 = block_sum512(bv[t] * wo, red);
            if (t == 0) ws[WS_CONST] += c2;
        }
        __syncthreads();
        const int fi = t & 63, ec = t >> 6;
        const int f0 = (blk - 64) * 64;
        float p = 0.0f;
        for (int e = ec * 64; e < ec * 64 + 64; ++e)
            p = fmaf(sh2[e], Wv[e * 512 + f0 + fi], p);  // coalesced in fi
        part[ec][fi] = p;
        __syncthreads();
        if (t < 64) {
            float ssum = 0.0f;
#pragma unroll
            for (int c = 0; c < 8; ++c) ssum += part[c][t];
            ws[WS_WV2 + f0 + t] = ssum;
        }
    } else {
        sh[t] = zb[t];
        __syncthreads();
        float q = 0.0f;
        for (int e = 0; e < 512; ++e)
            q = fmaf(Wq[t * 512 + e], sh[e], q);
        sh2[t] = q + bq[t];
        __syncthreads();
        const int ci = t & 63, fc = t >> 6;
        const int c0 = (blk - 72) * 64;
        float p = 0.0f;
        for (int f = fc * 64; f < fc * 64 + 64; ++f)
            p = fmaf(sh2[f], Wk[f * 512 + c0 + ci], p);  // coalesced in ci
        part[fc][ci] = p;
        __syncthreads();
        if (t < 64) {
            float ssum = 0.0f;
#pragma unroll
            for (int c = 0; c < 8; ++c) ssum += part[c][t];
            ws[WS_T + c0 + t] = ssum;
        }
    }
}

// ---------------------------------------------------------------------------
// K3: 64 blocks (one per chart k) x 512 threads.
//  wkc[f] = sum_c ce[k,c]*Wk[f,c]
//  G[k,d] = sum_f wkc[f]*P1[f,d]        -> stored transposed Gt[d][k]
//  ck0[k] = ce[k,:].t ,  cvw[k] = ce[k,:].wv2
// ---------------------------------------------------------------------------
__global__ __launch_bounds__(512) void k_charts(
    const float* __restrict__ chart_emb, const float* __restrict__ Wk,
    float* __restrict__ ws)
{
    __shared__ float ce[512];
    __shared__ float wkc[512];
    __shared__ float part[8][64];
    __shared__ float red[8];
    const int k = blockIdx.x, t = threadIdx.x;
    ce[t] = chart_emb[k * 512 + t];
    __syncthreads();
    float a = 0.0f;
    for (int c = 0; c < 512; ++c)
        a = fmaf(ce[c], Wk[t * 512 + c], a);
    wkc[t] = a;
    const float c0v = block_sum512(ce[t] * ws[WS_T + t], red);   // has syncs
    const float cvv = block_sum512(ce[t] * ws[WS_WV2 + t], red);
    if (t == 0) { ws[WS_CK0 + k] = c0v; ws[WS_CVW + k] = cvv; }
    __syncthreads();
    const int fc = t >> 6, d = t & 63;
    float g = 0.0f;
    for (int f = fc * 64; f < fc * 64 + 64; ++f)
        g = fmaf(wkc[f], ws[WS_P1 + f * 64 + d], g);
    part[fc][d] = g;
    __syncthreads();
    if (t < 64) {
        float ssum = 0.0f;
#pragma unroll
        for (int c = 0; c < 8; ++c) ssum += part[c][t];
        ws[WS_GT + t * 64 + k] = ssum;   // Gt[d][k], t plays role of d
    }
}

// ---------------------------------------------------------------------------
// K4: main. 256 blocks x 256 threads; each wave handles 4 rows.
//  lane = k. score_k = rw*(z.G[k] + ck0[k])/sqrt(DM) - geo*acosh(arg)^2
//  out[b] = sum_k softmax(score)_k * rw_k * cvw_k + const
// ---------------------------------------------------------------------------
__global__ __launch_bounds__(256) void k_main(
    const float* __restrict__ z, const float* __restrict__ rw,
    const float* __restrict__ geo, const float* __restrict__ ws,
    float* __restrict__ out)
{
    __shared__ float sGt[4096];
    __shared__ float sYt[4096];
    __shared__ float sCvw[64], sCk0[64], sNy2[64], sSc[2];
    const int t = threadIdx.x;
    for (int i = t; i < 4096; i += 256) {
        sGt[i] = ws[WS_GT + i];
        sYt[i] = ws[WS_YT + i];
    }
    if (t < 64) {
        sCvw[t] = ws[WS_CVW + t];
        sCk0[t] = ws[WS_CK0 + t];
        sNy2[t] = ws[WS_NY2 + t];
    }
    if (t == 0) { sSc[0] = ws[WS_CONST]; sSc[1] = geo[0]; }
    __syncthreads();
    const int wid = t >> 6, lane = t & 63;
    const float gs = sSc[1], cst = sSc[0];
#pragma unroll
    for (int r = 0; r < 4; ++r) {
        const int b = blockIdx.x * 16 + wid * 4 + r;
        const float zl = z[b * 64 + lane];
        const float rwk = rw[b * 64 + lane];
        float dot = 0.0f, diff2 = 0.0f, nz2 = 0.0f;
#pragma unroll 8
        for (int dd = 0; dd < 64; ++dd) {
            const float zd = __shfl(zl, dd);
            nz2 = fmaf(zd, zd, nz2);
            dot = fmaf(zd, sGt[dd * 64 + lane], dot);
            const float df = zd - sYt[dd * 64 + lane];
            diff2 = fmaf(df, df, diff2);
        }
        const float den = (1.0f - nz2) * (1.0f - sNy2[lane]);
        float arg = 1.0f + 2.0f * diff2 / fmaxf(den, 1e-12f);
        arg = fmaxf(arg, 1.0f + 1e-7f);
        const float dg = acoshf(arg);
        const float score = rwk * (dot + sCk0[lane]) / sqrtf(512.0f)
                          - gs * dg * dg;
        float m = score;
#pragma unroll
        for (int o = 32; o; o >>= 1) m = fmaxf(m, __shfl_xor(m, o));
        const float e = expf(score - m);
        float s1 = e, s2 = e * rwk * sCvw[lane];
#pragma unroll
        for (int o = 32; o; o >>= 1) { s1 += __shfl_xor(s1, o); s2 += __shfl_xor(s2, o); }
        if (lane == 0) out[b] = s2 / s1 + cst;
    }
}

extern "C" void kernel_launch(void* const* d_in, const int* in_sizes, int n_in,
                              void* d_out, int out_size, void* d_ws, size_t ws_size,
                              hipStream_t stream)
{
    (void)in_sizes; (void)n_in; (void)out_size; (void)ws_size;
    const float* z   = (const float*)d_in[0];
    const float* rw  = (const float*)d_in[1];
    const float* cem = (const float*)d_in[2];
    const float* cc  = (const float*)d_in[3];
    const float* zW  = (const float*)d_in[4];
    const float* zb  = (const float*)d_in[5];
    const float* Wq  = (const float*)d_in[6];
    const float* bq  = (const float*)d_in[7];
    const float* Wk  = (const float*)d_in[8];
    // d_in[9] = bk: softmax-shift-invariant, provably unused
    const float* Wv  = (const float*)d_in[10];
    const float* bv  = (const float*)d_in[11];
    const float* Wo  = (const float*)d_in[12];
    const float* bo  = (const float*)d_in[13];
    const float* geo = (const float*)d_in[14];
    const float* vW  = (const float*)d_in[15];
    const float* vb  = (const float*)d_in[16];
    float* ws  = (float*)d_ws;
    float* out = (float*)d_out;

    hipLaunchKernelGGL(k_setup,  dim3(1),   dim3(512), 0, stream, zW, vW, bo, vb, cc, ws);
    hipLaunchKernelGGL(k_mats,   dim3(80),  dim3(512), 0, stream, zW, Wq, Wo, Wv, Wk, zb, bq, bv, ws);
    hipLaunchKernelGGL(k_charts, dim3(64),  dim3(512), 0, stream, cem, Wk, ws);
    hipLaunchKernelGGL(k_main,   dim3(256), dim3(256), 0, stream, z, rw, geo, ws, out);
}

// Round 2
// 55.847 us; speedup vs baseline: 2.2738x; 2.2738x over previous
//
#include <hip/hip_runtime.h>
#include <math.h>

// dims: B=4096, D=64, K=64, DM=512
// Workspace layout (float offsets)
#define WS_INV   0
#define WS_C1    1            // bo.w + vb
#define WS_CBV   8            // [8..16) partial bv.wo per wo-block
#define WS_W     16           // 512
#define WS_QZB   528          // 512
#define WS_CK0   1040         // 64
#define WS_NY2   1104         // 64
#define WS_YT    1168         // 4096  Yt[d][k]
#define WS_CVP   5264         // 8*64 partial cvw
#define WS_T1    8192         // T1t[f][k]  (T1[k,f] = CE[k]·Wk[f,:])
#define WS_V1    40960        // V1t[e][k]
#define WS_P1    73728        // P1[f][d]   (Wq@zW, unscaled)
#define WS_GP    106496       // 2*4096 partial Gt[d][k]
// total 114688 floats = 448 KB

#define BIGF 32832            // floats: [64][513] transposed pad (also >= 512*64)
#define AUXF 1104
#define K1_LDS ((BIGF + AUXF) * 4)   // 135744 B
#define K2_LDS (33280 * 4)           // 133120 B (2 x [256][65])

__device__ __forceinline__ float wave_sum(float x) {
#pragma unroll
    for (int o = 32; o; o >>= 1) x += __shfl_xor(x, o);
    return x;
}

__device__ __forceinline__ float block_sum512(float v, float* red) {
    float s = wave_sum(v);
    const int wid = threadIdx.x >> 6;
    __syncthreads();
    if ((threadIdx.x & 63) == 0) red[wid] = s;
    __syncthreads();
    float t2 = 0.0f;
#pragma unroll
    for (int i = 0; i < 8; ++i) t2 += red[i];
    return t2;
}

// ===========================================================================
// K1: 202 blocks x 512 threads. All blocks depend only on raw inputs.
//  b0      : zW power iteration (LDS-staged, transposed padded) -> inv_sigma
//  b1      : vW spectral chain -> w, const1; project chart_centers -> Yt, ny2
//  b2..9   : qzb = Wq@zb + bq (64-f tiles)
//  b10..73 : T1t[f][k] = CE[k]·Wk[f,:]   (CE staged in LDS [64][513])
//  b74..137: V1t[e][k] = CE[k]·Wv[e,:]
//  b138..201: P1[f][d] = Wq[f,:]·zW[:,d] (zW staged in LDS [512][64])
// ===========================================================================
__global__ __launch_bounds__(512) void k_pre(
    const float* __restrict__ zW, const float* __restrict__ vW,
    const float* __restrict__ bo, const float* __restrict__ vb,
    const float* __restrict__ cc, const float* __restrict__ zb,
    const float* __restrict__ Wq, const float* __restrict__ bq,
    const float* __restrict__ Wk, const float* __restrict__ Wv,
    const float* __restrict__ ce, float* __restrict__ ws)
{
    extern __shared__ float smem[];
    float* big = smem;            // BIGF floats
    float* aux = smem + BIGF;     // AUXF floats
    const int blk = blockIdx.x, t = threadIdx.x;

    if (blk == 0) {
        // ---- stage zW transposed: big[d*513 + e] = zW[e*64 + d] ----
        for (int i = 0; i < 64; ++i) {
            const int li = i * 512 + t;
            const int e = li >> 6, d = li & 63;
            big[d * 513 + e] = zW[li];
        }
        __syncthreads();
        float* ush = aux;          // 512
        float* vsh = aux + 512;    // 64
        float* part = aux + 576;   // 512
        float* red = aux + 1088;   // 8
        const int d = t & 63, ch = t >> 6;
        ush[t] = 1.0f / (sqrtf(512.0f) + 1e-12f);
        __syncthreads();
        float upre = 0.0f;
        for (int it = 0; it < 5; ++it) {
            float pv = 0.0f;
#pragma unroll 8
            for (int e = ch * 64; e < ch * 64 + 64; ++e)
                pv = fmaf(big[d * 513 + e], ush[e], pv);
            part[ch * 64 + d] = pv;
            __syncthreads();
            if (t < 64) {
                float vd = 0.0f;
#pragma unroll
                for (int c = 0; c < 8; ++c) vd += part[c * 64 + t];
                const float nv = sqrtf(wave_sum(vd * vd));
                vsh[t] = vd / (nv + 1e-12f);
            }
            __syncthreads();
            float ui = 0.0f;
#pragma unroll 8
            for (int dd = 0; dd < 64; ++dd)
                ui = fmaf(big[dd * 513 + t], vsh[dd], ui);
            upre = ui;
            const float nu = sqrtf(block_sum512(ui * ui, red));
            ush[t] = ui / (nu + 1e-12f);
            __syncthreads();
        }
        const float sig = block_sum512(ush[t] * upre, red);
        if (t == 0) ws[WS_INV] = 1.0f / sig;

    } else if (blk == 1) {
        float* red = aux;
        // ---- vW spectral chain (u scalar) ----
        const float vwt = vW[t];
        float uv = 1.0f / (1.0f + 1e-12f);
        float s = 0.0f;
        for (int it = 0; it < 5; ++it) {
            const float tv = vwt * uv;
            const float nv = sqrtf(block_sum512(tv * tv, red));
            const float vcur = tv / (nv + 1e-12f);
            s = block_sum512(vwt * vcur, red);
            uv = s / (fabsf(s) + 1e-12f);
        }
        const float sigv = uv * s;
        const float wv = vwt / sigv;
        ws[WS_W + t] = wv;
        const float cp = block_sum512(bo[t] * wv, red);
        if (t == 0) ws[WS_C1] = cp + vb[0];
        // ---- project chart centers ----
        if (t < 64) {
            float n2 = 0.0f;
            for (int dd = 0; dd < 64; ++dd) {
                const float c = cc[t * 64 + dd];
                n2 = fmaf(c, c, n2);
            }
            const float n = sqrtf(n2);
            const float scale = fminf(1.0f, (1.0f - 1e-5f) / fmaxf(n, 1e-12f));
            float s2 = 0.0f;
            for (int dd = 0; dd < 64; ++dd) {
                const float yv = cc[t * 64 + dd] * scale;
                ws[WS_YT + dd * 64 + t] = yv;
                s2 = fmaf(yv, yv, s2);
            }
            ws[WS_NY2 + t] = s2;
        }

    } else if (blk < 10) {
        // ---- qzb = Wq@zb + bq, 64-row tile ----
        aux[t] = zb[t];
        __syncthreads();
        const int f0 = (blk - 2) * 64;
        const int fl = t & 63, ch = t >> 6;
        float s = 0.0f;
#pragma unroll 8
        for (int e = ch * 64; e < ch * 64 + 64; ++e)
            s = fmaf(Wq[(f0 + fl) * 512 + e], aux[e], s);
        float* part = aux + 512;
        part[ch * 64 + fl] = s;
        __syncthreads();
        if (t < 64) {
            float q = 0.0f;
#pragma unroll
            for (int c = 0; c < 8; ++c) q += part[c * 64 + t];
            ws[WS_QZB + f0 + t] = q + bq[f0 + t];
        }

    } else if (blk < 138) {
        // ---- T1t / V1t: stage CE [64][513], per-thread dot with uniform W row
        for (int i = 0; i < 64; ++i) {
            const int li = i * 512 + t;
            const int k = li >> 9, c = li & 511;
            big[k * 513 + c] = ce[li];
        }
        __syncthreads();
        const int lane = t & 63;
        const bool isT = (blk < 74);
        const int f = (isT ? (blk - 10) : (blk - 74)) * 8 + (t >> 6);
        const float* W = isT ? Wk : Wv;
        float acc = 0.0f;
#pragma unroll 8
        for (int c = 0; c < 512; ++c)
            acc = fmaf(W[f * 512 + c], big[lane * 513 + c], acc);
        ws[(isT ? WS_T1 : WS_V1) + f * 64 + lane] = acc;

    } else {
        // ---- P1[f][d] = Wq[f,:]·zW[:,d], zW staged natural [512][64] ----
        for (int i = 0; i < 64; ++i) {
            const int li = i * 512 + t;
            big[li] = zW[li];
        }
        __syncthreads();
        const int d = t & 63;
        const int f = (blk - 138) * 8 + (t >> 6);
        float acc = 0.0f;
#pragma unroll 8
        for (int e = 0; e < 512; ++e)
            acc = fmaf(Wq[f * 512 + e], big[e * 64 + d], acc);
        ws[WS_P1 + f * 64 + d] = acc;
    }
}

// ===========================================================================
// K2: 11 blocks x 512 threads.
//  b0..7 : wo e-tile (Wo^T w), then partial cvw[k] += V1t[e,k]·wo[e],
//          partial bv·wo
//  b8..9 : partial Gt[d][k] over f-half: sum_f T1t[f][k] * P1[f][d]
//  b10   : ck0[k] = sum_f T1t[f][k] * qzb[f]
// ===========================================================================
__global__ __launch_bounds__(512) void k_mid(
    const float* __restrict__ Wo, const float* __restrict__ bv,
    float* __restrict__ ws)
{
    extern __shared__ float smem[];
    const int blk = blockIdx.x, t = threadIdx.x;

    if (blk < 8) {
        float* wl = smem;          // 512
        float* red = smem + 512;   // 512
        float* wol = smem + 1024;  // 64
        wl[t] = ws[WS_W + t];
        __syncthreads();
        const int e0 = blk * 64;
        const int e = t & 63, gc = t >> 6;
        float s = 0.0f;
#pragma unroll 8
        for (int g = gc * 64; g < gc * 64 + 64; ++g)
            s = fmaf(Wo[g * 512 + e0 + e], wl[g], s);
        red[gc * 64 + e] = s;
        __syncthreads();
        if (t < 64) {
            float wo = 0.0f;
#pragma unroll
            for (int c = 0; c < 8; ++c) wo += red[c * 64 + t];
            wol[t] = wo;
        }
        __syncthreads();
        // partial cvw
        const int k = t & 63, ec = t >> 6;
        float cv = 0.0f;
#pragma unroll
        for (int j = 0; j < 8; ++j)
            cv = fmaf(ws[WS_V1 + (e0 + ec * 8 + j) * 64 + k], wol[ec * 8 + j], cv);
        __syncthreads();
        red[ec * 64 + k] = cv;
        __syncthreads();
        if (t < 64) {
            float c2 = 0.0f;
#pragma unroll
            for (int c = 0; c < 8; ++c) c2 += red[c * 64 + t];
            ws[WS_CVP + blk * 64 + t] = c2;
        }
        // partial bv.wo
        if (t < 64) {
            float b = bv[e0 + t] * wol[t];
            b = wave_sum(b);
            if (t == 0) ws[WS_CBV + blk] = b;
        }

    } else if (blk < 10) {
        // Gt partial over half the f range
        float* A = smem;                  // [256][65] T1t tile
        float* Bm = smem + 256 * 65;      // [256][65] P1 tile
        const int p = blk - 8;
        const int f0 = p * 256;
        for (int i = 0; i < 32; ++i) {
            const int li = i * 512 + t;
            const int f = li >> 6, k = li & 63;
            A[f * 65 + k]  = ws[WS_T1 + f0 * 64 + li];
            Bm[f * 65 + k] = ws[WS_P1 + f0 * 64 + li];
        }
        __syncthreads();
        const int k = t & 63, dg = t >> 6;
        float acc[8];
#pragma unroll
        for (int j = 0; j < 8; ++j) acc[j] = 0.0f;
        for (int f = 0; f < 256; ++f) {
            const float a = A[f * 65 + k];
#pragma unroll
            for (int j = 0; j < 8; ++j)
                acc[j] = fmaf(a, Bm[f * 65 + dg * 8 + j], acc[j]);
        }
#pragma unroll
        for (int j = 0; j < 8; ++j)
            ws[WS_GP + p * 4096 + (dg * 8 + j) * 64 + k] = acc[j];

    } else {
        // ck0 = T1 @ qzb
        float* ql = smem;          // 512
        float* red = smem + 512;   // 512
        ql[t] = ws[WS_QZB + t];
        __syncthreads();
        const int k = t & 63, fc = t >> 6;
        float s = 0.0f;
#pragma unroll 8
        for (int f = fc * 64; f < fc * 64 + 64; ++f)
            s = fmaf(ws[WS_T1 + f * 64 + k], ql[f], s);
        red[fc * 64 + k] = s;
        __syncthreads();
        if (t < 64) {
            float c0 = 0.0f;
#pragma unroll
            for (int c = 0; c < 8; ++c) c0 += red[c * 64 + t];
            ws[WS_CK0 + t] = c0;
        }
    }
}

// ===========================================================================
// K3: main. 256 blocks x 256 threads; each wave handles 4 rows, lane = k.
// ===========================================================================
__global__ __launch_bounds__(256) void k_main(
    const float* __restrict__ z, const float* __restrict__ rw,
    const float* __restrict__ geo, const float* __restrict__ ws,
    float* __restrict__ out)
{
    __shared__ float sGt[4096];
    __shared__ float sYt[4096];
    __shared__ float sCvw[64], sCk0[64], sNy2[64], sSc[2];
    const int t = threadIdx.x;
    const float inv_s = ws[WS_INV];
    for (int i = t; i < 4096; i += 256) {
        sGt[i] = inv_s * (ws[WS_GP + i] + ws[WS_GP + 4096 + i]);
        sYt[i] = ws[WS_YT + i];
    }
    if (t < 64) {
        float cv = 0.0f;
#pragma unroll
        for (int p = 0; p < 8; ++p) cv += ws[WS_CVP + p * 64 + t];
        sCvw[t] = cv;
        sCk0[t] = ws[WS_CK0 + t];
        sNy2[t] = ws[WS_NY2 + t];
    }
    if (t == 0) {
        float cst = ws[WS_C1];
#pragma unroll
        for (int p = 0; p < 8; ++p) cst += ws[WS_CBV + p];
        sSc[0] = cst; sSc[1] = geo[0];
    }
    __syncthreads();
    const int wid = t >> 6, lane = t & 63;
    const float gs = sSc[1], cst = sSc[0];
#pragma unroll
    for (int r = 0; r < 4; ++r) {
        const int b = blockIdx.x * 16 + wid * 4 + r;
        const float zl = z[b * 64 + lane];
        const float rwk = rw[b * 64 + lane];
        float dot = 0.0f, diff2 = 0.0f, nz2 = 0.0f;
#pragma unroll 8
        for (int dd = 0; dd < 64; ++dd) {
            const float zd = __shfl(zl, dd);
            nz2 = fmaf(zd, zd, nz2);
            dot = fmaf(zd, sGt[dd * 64 + lane], dot);
            const float df = zd - sYt[dd * 64 + lane];
            diff2 = fmaf(df, df, diff2);
        }
        const float den = (1.0f - nz2) * (1.0f - sNy2[lane]);
        float arg = 1.0f + 2.0f * diff2 / fmaxf(den, 1e-12f);
        arg = fmaxf(arg, 1.0f + 1e-7f);
        const float dg = acoshf(arg);
        const float score = rwk * (dot + sCk0[lane]) / sqrtf(512.0f)
                          - gs * dg * dg;
        float m = score;
#pragma unroll
        for (int o = 32; o; o >>= 1) m = fmaxf(m, __shfl_xor(m, o));
        const float e = expf(score - m);
        float s1 = e, s2 = e * rwk * sCvw[lane];
#pragma unroll
        for (int o = 32; o; o >>= 1) { s1 += __shfl_xor(s1, o); s2 += __shfl_xor(s2, o); }
        if (lane == 0) out[b] = s2 / s1 + cst;
    }
}

extern "C" void kernel_launch(void* const* d_in, const int* in_sizes, int n_in,
                              void* d_out, int out_size, void* d_ws, size_t ws_size,
                              hipStream_t stream)
{
    (void)in_sizes; (void)n_in; (void)out_size; (void)ws_size;
    const float* z   = (const float*)d_in[0];
    const float* rw  = (const float*)d_in[1];
    const float* cem = (const float*)d_in[2];
    const float* cc  = (const float*)d_in[3];
    const float* zW  = (const float*)d_in[4];
    const float* zb  = (const float*)d_in[5];
    const float* Wq  = (const float*)d_in[6];
    const float* bq  = (const float*)d_in[7];
    const float* Wk  = (const float*)d_in[8];
    // d_in[9] = bk: softmax-shift-invariant, provably unused
    const float* Wv  = (const float*)d_in[10];
    const float* bv  = (const float*)d_in[11];
    const float* Wo  = (const float*)d_in[12];
    const float* bo  = (const float*)d_in[13];
    const float* geo = (const float*)d_in[14];
    const float* vW  = (const float*)d_in[15];
    const float* vb  = (const float*)d_in[16];
    float* ws  = (float*)d_ws;
    float* out = (float*)d_out;

    hipLaunchKernelGGL(k_pre,  dim3(202), dim3(512), K1_LDS, stream,
                       zW, vW, bo, vb, cc, zb, Wq, bq, Wk, Wv, cem, ws);
    hipLaunchKernelGGL(k_mid,  dim3(11),  dim3(512), K2_LDS, stream, Wo, bv, ws);
    hipLaunchKernelGGL(k_main, dim3(256), dim3(256), 0, stream, z, rw, geo, ws, out);
}

// Round 3
// 32.902 us; speedup vs baseline: 3.8596x; 1.6974x over previous
//
#include <hip/hip_runtime.h>
#include <math.h>

// dims: B=4096, D=64, K=64, DM=512
// Workspace layout (float offsets)
#define WS_INV    0
#define WS_INVSV  1
#define WS_BOVW   2
#define WS_BVWO   3
#define WS_N2V    4
#define WS_COLSUM 64          // 64
#define WS_A      128         // 64*64 = 4096
#define WS_WO0    4224        // 512
#define WS_QZB    4736        // 512
#define WS_CK0    5248        // 64
#define WS_CVW    5312        // 64
#define WS_NY2    5376        // 64
#define WS_YT     5440        // 4096
#define WS_T1     16384       // T1t[f][k] 512*64
#define WS_V1     49152       // V1t[e][k] 512*64
#define WS_P1     81920       // P1[f][d]  512*64
#define WS_GP     114688      // 4 * 4096 partial Gt[d][k]

#define PRE_LDSB  (36928 * 4)   // 147712 B
#define MID_LDSB  (16384 * 4)   // 65536 B

__device__ __forceinline__ float wave_sum(float x) {
#pragma unroll
    for (int o = 32; o; o >>= 1) x += __shfl_xor(x, o);
    return x;
}

__device__ __forceinline__ float block_sum512(float v, float* red) {
    float s = wave_sum(v);
    const int wid = threadIdx.x >> 6;
    __syncthreads();
    if ((threadIdx.x & 63) == 0) red[wid] = s;
    __syncthreads();
    float t2 = 0.0f;
#pragma unroll
    for (int i = 0; i < 8; ++i) t2 += red[i];
    return t2;
}

// ===========================================================================
// K1: 217 blocks x 512 threads. All level-0 (inputs only).
//  b0..127  : T1t & V1t, 4 f-rows each of both (CE staged, warp-c-split)
//  b128..191: P1[f][d] 8 f-rows each (zW staged, warp-e-split)
//  b192..199: A = zW^T zW, 8 rows each (+ colsum on b192)
//  b200..207: qzb = Wq@zb + bq (64 f each, warp-per-8f wave-reduce)
//  b208..215: wo0 = Wo^T vW (64 e each)
//  b216     : n2v, bo.vW, chart-center projection -> Yt, ny2
// ===========================================================================
__global__ __launch_bounds__(512) void k_pre(
    const float* __restrict__ zW, const float* __restrict__ zb,
    const float* __restrict__ Wq, const float* __restrict__ bq,
    const float* __restrict__ Wk, const float* __restrict__ Wv,
    const float* __restrict__ Wo, const float* __restrict__ ce,
    const float* __restrict__ cc, const float* __restrict__ vW,
    const float* __restrict__ bo, float* __restrict__ ws)
{
    extern __shared__ float sm[];
    const int blk = blockIdx.x, t = threadIdx.x;
    const int lane = t & 63, w = t >> 6;

    if (blk < 128) {
        // ---------------- T1t / V1t ----------------
        const int f0 = blk * 4;
        float* ces = sm;            // 64*513
        float* wkv = sm + 32832;    // 8*512
#pragma unroll 4
        for (int i = 0; i < 64; ++i) {
            const int idx = i * 512 + t;              // k*512 + c
            ces[(idx >> 9) * 513 + (idx & 511)] = ce[idx];
        }
        {
            const float4* Wk4 = (const float4*)Wk;
            const float4* Wv4 = (const float4*)Wv;
            float4* wkv4 = (float4*)wkv;
#pragma unroll
            for (int i = 0; i < 2; ++i) {
                const int idx = i * 512 + t;          // a*128 + c4
                const int a = idx >> 7, c4 = idx & 127;
                wkv4[idx] = (a < 4) ? Wk4[(f0 + a) * 128 + c4]
                                    : Wv4[(f0 + a - 4) * 128 + c4];
            }
        }
        __syncthreads();
        float acc[8];
#pragma unroll
        for (int a = 0; a < 8; ++a) acc[a] = 0.0f;
        const int c0 = w * 64;
#pragma unroll 2
        for (int q4 = 0; q4 < 16; ++q4) {
            const int c = c0 + q4 * 4;
            const float cv0 = ces[lane * 513 + c + 0];
            const float cv1 = ces[lane * 513 + c + 1];
            const float cv2 = ces[lane * 513 + c + 2];
            const float cv3 = ces[lane * 513 + c + 3];
#pragma unroll
            for (int a = 0; a < 8; ++a) {
                const float4 wv4 = *(const float4*)&wkv[a * 512 + c];
                acc[a] = fmaf(wv4.x, cv0, acc[a]);
                acc[a] = fmaf(wv4.y, cv1, acc[a]);
                acc[a] = fmaf(wv4.z, cv2, acc[a]);
                acc[a] = fmaf(wv4.w, cv3, acc[a]);
            }
        }
        __syncthreads();
        float* part = sm;                              // reuse, 64*65
#pragma unroll
        for (int a = 0; a < 8; ++a) part[(a * 8 + w) * 65 + lane] = acc[a];
        __syncthreads();
        {
            float s = 0.0f;
#pragma unroll
            for (int ww = 0; ww < 8; ++ww) s += part[(w * 8 + ww) * 65 + lane];
            if (w < 4) ws[WS_T1 + (f0 + w) * 64 + lane] = s;
            else       ws[WS_V1 + (f0 + w - 4) * 64 + lane] = s;
        }

    } else if (blk < 192) {
        // ---------------- P1 ----------------
        const int f0 = (blk - 128) * 8;
        float* zl = sm;             // 512*64
        float* wq = sm + 32768;     // 8*512
        {
            const float4* zW4 = (const float4*)zW;
            float4* zl4 = (float4*)zl;
#pragma unroll 4
            for (int i = 0; i < 16; ++i) zl4[i * 512 + t] = zW4[i * 512 + t];
            const float4* Wq4 = (const float4*)Wq;
            float4* wq4 = (float4*)wq;
#pragma unroll
            for (int i = 0; i < 2; ++i)
                wq4[i * 512 + t] = Wq4[f0 * 128 + i * 512 + t];
        }
        __syncthreads();
        float acc[8];
#pragma unroll
        for (int a = 0; a < 8; ++a) acc[a] = 0.0f;
        const int e0 = w * 64;
#pragma unroll 2
        for (int q4 = 0; q4 < 16; ++q4) {
            const int e = e0 + q4 * 4;
            const float z0 = zl[(e + 0) * 64 + lane];
            const float z1 = zl[(e + 1) * 64 + lane];
            const float z2 = zl[(e + 2) * 64 + lane];
            const float z3 = zl[(e + 3) * 64 + lane];
#pragma unroll
            for (int fi = 0; fi < 8; ++fi) {
                const float4 q4v = *(const float4*)&wq[fi * 512 + e];
                acc[fi] = fmaf(q4v.x, z0, acc[fi]);
                acc[fi] = fmaf(q4v.y, z1, acc[fi]);
                acc[fi] = fmaf(q4v.z, z2, acc[fi]);
                acc[fi] = fmaf(q4v.w, z3, acc[fi]);
            }
        }
        __syncthreads();
        float* part = sm;
#pragma unroll
        for (int a = 0; a < 8; ++a) part[(a * 8 + w) * 65 + lane] = acc[a];
        __syncthreads();
        {
            float s = 0.0f;
#pragma unroll
            for (int ww = 0; ww < 8; ++ww) s += part[(w * 8 + ww) * 65 + lane];
            ws[WS_P1 + (f0 + w) * 64 + lane] = s;
        }

    } else if (blk < 200) {
        // ---------------- A = zW^T zW (+ colsum on first) ----------------
        const int r0 = (blk - 192) * 8;
        float* zl = sm;
        {
            const float4* zW4 = (const float4*)zW;
            float4* zl4 = (float4*)zl;
#pragma unroll 4
            for (int i = 0; i < 16; ++i) zl4[i * 512 + t] = zW4[i * 512 + t];
        }
        __syncthreads();
        float acc[8];
#pragma unroll
        for (int a = 0; a < 8; ++a) acc[a] = 0.0f;
        float cs = 0.0f;
        const int e0 = w * 64;
#pragma unroll 2
        for (int q4 = 0; q4 < 16; ++q4) {
            const int e = e0 + q4 * 4;
#pragma unroll
            for (int j = 0; j < 4; ++j) {
                const float zv = zl[(e + j) * 64 + lane];
                cs += zv;
                const float4 b0 = *(const float4*)&zl[(e + j) * 64 + r0];
                const float4 b1 = *(const float4*)&zl[(e + j) * 64 + r0 + 4];
                acc[0] = fmaf(b0.x, zv, acc[0]);
                acc[1] = fmaf(b0.y, zv, acc[1]);
                acc[2] = fmaf(b0.z, zv, acc[2]);
                acc[3] = fmaf(b0.w, zv, acc[3]);
                acc[4] = fmaf(b1.x, zv, acc[4]);
                acc[5] = fmaf(b1.y, zv, acc[5]);
                acc[6] = fmaf(b1.z, zv, acc[6]);
                acc[7] = fmaf(b1.w, zv, acc[7]);
            }
        }
        __syncthreads();
        float* part = sm;            // 64*65
        float* part2 = sm + 4160;    // 8*65
#pragma unroll
        for (int a = 0; a < 8; ++a) part[(a * 8 + w) * 65 + lane] = acc[a];
        if (blk == 192) part2[w * 65 + lane] = cs;
        __syncthreads();
        {
            float s = 0.0f;
#pragma unroll
            for (int ww = 0; ww < 8; ++ww) s += part[(w * 8 + ww) * 65 + lane];
            ws[WS_A + (r0 + w) * 64 + lane] = s;
        }
        if (blk == 192 && t < 64) {
            float s = 0.0f;
#pragma unroll
            for (int ww = 0; ww < 8; ++ww) s += part2[ww * 65 + t];
            ws[WS_COLSUM + t] = s;
        }

    } else if (blk < 208) {
        // ---------------- qzb ----------------
        const int f0 = (blk - 200) * 64;
        float zbr[8];
#pragma unroll
        for (int i = 0; i < 8; ++i) zbr[i] = zb[i * 64 + lane];
#pragma unroll
        for (int ff = 0; ff < 8; ++ff) {
            const int f = f0 + w * 8 + ff;
            float s = 0.0f;
#pragma unroll
            for (int i = 0; i < 8; ++i)
                s = fmaf(Wq[f * 512 + i * 64 + lane], zbr[i], s);
            s = wave_sum(s);
            if (lane == 0) ws[WS_QZB + f] = s + bq[f];
        }

    } else if (blk < 216) {
        // ---------------- wo0 = Wo^T vW ----------------
        const int e0 = (blk - 208) * 64;
        float s = 0.0f;
#pragma unroll 4
        for (int gi = 0; gi < 64; ++gi) {
            const int g = w * 64 + gi;
            s = fmaf(Wo[g * 512 + e0 + lane], vW[g], s);
        }
        float* part = sm;
        part[w * 65 + lane] = s;
        __syncthreads();
        if (t < 64) {
            float o = 0.0f;
#pragma unroll
            for (int ww = 0; ww < 8; ++ww) o += part[ww * 65 + t];
            ws[WS_WO0 + e0 + t] = o;
        }

    } else {
        // ---------------- misc: n2v, bo.vW, cc projection ----------------
        float* red = sm;
        const float vwt = vW[t];
        const float n2v = block_sum512(vwt * vwt, red);
        if (t == 0) ws[WS_N2V] = n2v;
        const float bv_ = block_sum512(bo[t] * vwt, red);
        if (t == 0) ws[WS_BOVW] = bv_;
        if (t < 64) {
            float n2 = 0.0f;
            for (int dd = 0; dd < 64; ++dd) {
                const float c = cc[t * 64 + dd];
                n2 = fmaf(c, c, n2);
            }
            const float n = sqrtf(n2);
            const float scale = fminf(1.0f, (1.0f - 1e-5f) / fmaxf(n, 1e-12f));
            float s2 = 0.0f;
            for (int dd = 0; dd < 64; ++dd) {
                const float yv = cc[t * 64 + dd] * scale;
                ws[WS_YT + dd * 64 + t] = yv;
                s2 = fmaf(yv, yv, s2);
            }
            ws[WS_NY2 + t] = s2;
        }
    }
}

// ===========================================================================
// K2: 7 blocks x 512 threads (level-1).
//  b0 : sigma power-iteration on A (1 wave) + bv.wo0 + sigma_v closed form
//  b1 : cvw0 = V1 @ wo0
//  b2 : ck0  = T1 @ qzb
//  b3..6: Gt partials over 128-f slices: GP[p][d][k] = sum_f T1t[f][k]*P1[f][d]
// ===========================================================================
__global__ __launch_bounds__(512) void k_mid(
    const float* __restrict__ bv, float* __restrict__ ws)
{
    extern __shared__ float sm[];
    const int blk = blockIdx.x, t = threadIdx.x;
    const int lane = t & 63, w = t >> 6;

    if (blk == 0) {
        float* As = sm;   // 64*65
#pragma unroll
        for (int i = 0; i < 8; ++i) {
            const int idx = i * 512 + t;
            As[(idx >> 6) * 65 + (idx & 63)] = ws[WS_A + idx];
        }
        __syncthreads();
        if (w == 0) {
            const int d = lane;
            const float u0val = 1.0f / (sqrtf(512.0f) + 1e-12f);
            const float x = ws[WS_COLSUM + d] * u0val;
            const float nx = sqrtf(wave_sum(x * x));
            float v = x / (nx + 1e-12f);
            float mv;
            for (int it = 0; it < 4; ++it) {
                mv = 0.0f;
                for (int j = 0; j < 64; ++j)
                    mv = fmaf(As[j * 65 + d], __shfl(v, j), mv);
                const float s1 = wave_sum(mv * v);
                const float s2 = wave_sum(mv * mv);
                const float n = sqrtf(s1);
                const float inv1 = 1.0f / (n + 1e-12f);
                const float ny = sqrtf(s2) * inv1;
                v = mv * inv1 / (ny + 1e-12f);
            }
            mv = 0.0f;
            for (int j = 0; j < 64; ++j)
                mv = fmaf(As[j * 65 + d], __shfl(v, j), mv);
            const float n5sq = wave_sum(mv * v);
            const float n5 = sqrtf(n5sq);
            const float sig = n5sq / (n5 + 1e-12f);
            if (lane == 0) ws[WS_INV] = 1.0f / sig;
        } else if (w == 1) {
            float s = 0.0f;
#pragma unroll
            for (int i = 0; i < 8; ++i)
                s = fmaf(bv[i * 64 + lane], ws[WS_WO0 + i * 64 + lane], s);
            s = wave_sum(s);
            if (lane == 0) ws[WS_BVWO] = s;
        } else if (w == 2 && lane == 0) {
            const float n2 = ws[WS_N2V];
            const float rn = sqrtf(n2);
            float u = 1.0f / (1.0f + 1e-12f), s = 0.0f;
            for (int it = 0; it < 5; ++it) {
                const float nv = fabsf(u) * rn;
                const float vs = u / (nv + 1e-12f);
                s = n2 * vs;
                u = s / (fabsf(s) + 1e-12f);
            }
            ws[WS_INVSV] = 1.0f / (u * s);
        }

    } else if (blk < 3) {
        const int mat = (blk == 1) ? WS_V1 : WS_T1;
        const int vec = (blk == 1) ? WS_WO0 : WS_QZB;
        const int dst = (blk == 1) ? WS_CVW : WS_CK0;
        float s = 0.0f;
#pragma unroll 4
        for (int i = 0; i < 64; ++i) {
            const int e = w * 64 + i;
            s = fmaf(ws[mat + e * 64 + lane], ws[vec + e], s);
        }
        float* part = sm;
        part[w * 65 + lane] = s;
        __syncthreads();
        if (t < 64) {
            float o = 0.0f;
#pragma unroll
            for (int ww = 0; ww < 8; ++ww) o += part[ww * 65 + t];
            ws[dst + t] = o;
        }

    } else {
        const int p = blk - 3;
        const int f0 = p * 128;
        float* T1s = sm;           // 128*64
        float* P1s = sm + 8192;    // 128*64
        {
            const float4* a4 = (const float4*)&ws[WS_T1 + f0 * 64];
            const float4* b4 = (const float4*)&ws[WS_P1 + f0 * 64];
            float4* T14 = (float4*)T1s;
            float4* P14 = (float4*)P1s;
#pragma unroll
            for (int i = 0; i < 4; ++i) {
                T14[i * 512 + t] = a4[i * 512 + t];
                P14[i * 512 + t] = b4[i * 512 + t];
            }
        }
        __syncthreads();
        float acc[8];
#pragma unroll
        for (int j = 0; j < 8; ++j) acc[j] = 0.0f;
        const int d0 = w * 8;
#pragma unroll 2
        for (int f = 0; f < 128; ++f) {
            const float a = T1s[f * 64 + lane];
            const float4 p0 = *(const float4*)&P1s[f * 64 + d0];
            const float4 p1 = *(const float4*)&P1s[f * 64 + d0 + 4];
            acc[0] = fmaf(a, p0.x, acc[0]);
            acc[1] = fmaf(a, p0.y, acc[1]);
            acc[2] = fmaf(a, p0.z, acc[2]);
            acc[3] = fmaf(a, p0.w, acc[3]);
            acc[4] = fmaf(a, p1.x, acc[4]);
            acc[5] = fmaf(a, p1.y, acc[5]);
            acc[6] = fmaf(a, p1.z, acc[6]);
            acc[7] = fmaf(a, p1.w, acc[7]);
        }
#pragma unroll
        for (int j = 0; j < 8; ++j)
            ws[WS_GP + p * 4096 + (d0 + j) * 64 + lane] = acc[j];
    }
}

// ===========================================================================
// K3: main. 256 blocks x 256 threads; each wave 4 rows, lane = k.
// ===========================================================================
__global__ __launch_bounds__(256) void k_main(
    const float* __restrict__ z, const float* __restrict__ rw,
    const float* __restrict__ geo, const float* __restrict__ vb,
    const float* __restrict__ ws, float* __restrict__ out)
{
    __shared__ float sGt[4096];
    __shared__ float sYt[4096];
    __shared__ float sCvw[64], sCk0[64], sNy2[64], sSc[2];
    const int t = threadIdx.x;
    const float inv_s = ws[WS_INV];
    const float inv_sv = ws[WS_INVSV];
    for (int i = t; i < 4096; i += 256) {
        sGt[i] = inv_s * (ws[WS_GP + i] + ws[WS_GP + 4096 + i]
                        + ws[WS_GP + 8192 + i] + ws[WS_GP + 12288 + i]);
        sYt[i] = ws[WS_YT + i];
    }
    if (t < 64) {
        sCvw[t] = inv_sv * ws[WS_CVW + t];
        sCk0[t] = ws[WS_CK0 + t];
        sNy2[t] = ws[WS_NY2 + t];
    }
    if (t == 0) {
        sSc[0] = inv_sv * (ws[WS_BVWO] + ws[WS_BOVW]) + vb[0];
        sSc[1] = geo[0];
    }
    __syncthreads();
    const int wid = t >> 6, lane = t & 63;
    const float gs = sSc[1], cst = sSc[0];
    const float rs512 = 0.04419417382415922f;   // 1/sqrt(512)
#pragma unroll
    for (int r = 0; r < 4; ++r) {
        const int b = blockIdx.x * 16 + wid * 4 + r;
        const float zl = z[b * 64 + lane];
        const float rwk = rw[b * 64 + lane];
        float dot = 0.0f, diff2 = 0.0f, nz2 = 0.0f;
#pragma unroll 8
        for (int dd = 0; dd < 64; ++dd) {
            const float zd = __shfl(zl, dd);
            nz2 = fmaf(zd, zd, nz2);
            dot = fmaf(zd, sGt[dd * 64 + lane], dot);
            const float df = zd - sYt[dd * 64 + lane];
            diff2 = fmaf(df, df, diff2);
        }
        const float den = (1.0f - nz2) * (1.0f - sNy2[lane]);
        float arg = 1.0f + 2.0f * diff2 / fmaxf(den, 1e-12f);
        arg = fmaxf(arg, 1.0f + 1e-7f);
        const float dg = acoshf(arg);
        const float score = rwk * (dot + sCk0[lane]) * rs512 - gs * dg * dg;
        float m = score;
#pragma unroll
        for (int o = 32; o; o >>= 1) m = fmaxf(m, __shfl_xor(m, o));
        const float e = expf(score - m);
        float s1 = e, s2 = e * rwk * sCvw[lane];
#pragma unroll
        for (int o = 32; o; o >>= 1) { s1 += __shfl_xor(s1, o); s2 += __shfl_xor(s2, o); }
        if (lane == 0) out[b] = s2 / s1 + cst;
    }
}

extern "C" void kernel_launch(void* const* d_in, const int* in_sizes, int n_in,
                              void* d_out, int out_size, void* d_ws, size_t ws_size,
                              hipStream_t stream)
{
    (void)in_sizes; (void)n_in; (void)out_size; (void)ws_size;
    const float* z   = (const float*)d_in[0];
    const float* rw  = (const float*)d_in[1];
    const float* cem = (const float*)d_in[2];
    const float* cc  = (const float*)d_in[3];
    const float* zW  = (const float*)d_in[4];
    const float* zb  = (const float*)d_in[5];
    const float* Wq  = (const float*)d_in[6];
    const float* bq  = (const float*)d_in[7];
    const float* Wk  = (const float*)d_in[8];
    // d_in[9] = bk: softmax-shift-invariant, provably unused
    const float* Wv  = (const float*)d_in[10];
    const float* bv  = (const float*)d_in[11];
    const float* Wo  = (const float*)d_in[12];
    const float* bo  = (const float*)d_in[13];
    const float* geo = (const float*)d_in[14];
    const float* vW  = (const float*)d_in[15];
    const float* vb  = (const float*)d_in[16];
    float* ws  = (float*)d_ws;
    float* out = (float*)d_out;

    hipLaunchKernelGGL(k_pre,  dim3(217), dim3(512), PRE_LDSB, stream,
                       zW, zb, Wq, bq, Wk, Wv, Wo, cem, cc, vW, bo, ws);
    hipLaunchKernelGGL(k_mid,  dim3(7),   dim3(512), MID_LDSB, stream, bv, ws);
    hipLaunchKernelGGL(k_main, dim3(256), dim3(256), 0, stream,
                       z, rw, geo, vb, ws, out);
}